// Round 6
// baseline (364.324 us; speedup 1.0000x reference)
//
#include <hip/hip_runtime.h>
#include <hip/hip_bf16.h>

typedef __attribute__((ext_vector_type(8))) short short8;
typedef __attribute__((ext_vector_type(4))) float f32x4;

constexpr int B_ = 4, S_ = 2048, D_ = 512, H_ = 8, DP_ = 64;
constexpr int M_ = B_ * S_;  // 8192 rows

__device__ __forceinline__ unsigned short f2b(float f) {
    __hip_bfloat16 h = __float2bfloat16(f);
    return *reinterpret_cast<unsigned short*>(&h);
}

#define MFMA16(a, b, c) __builtin_amdgcn_mfma_f32_16x16x32_bf16((a), (b), (c), 0, 0, 0)

// ---------------- weight transpose + convert: Wt[n][k] = bf16(W[k][n]) ----------------
__global__ __launch_bounds__(256)
void transpose_w(const float* __restrict__ w0, const float* __restrict__ w1,
                 const float* __restrict__ w2, const float* __restrict__ w3,
                 unsigned short* __restrict__ outw) {
    const float* in = (blockIdx.z == 0) ? w0 : (blockIdx.z == 1) ? w1
                     : (blockIdx.z == 2) ? w2 : w3;
    unsigned short* out = outw + (size_t)blockIdx.z * D_ * D_;
    __shared__ float t[64][65];
    int k0 = blockIdx.x * 64, n0 = blockIdx.y * 64;
    int tx = threadIdx.x & 63, ty = threadIdx.x >> 6;
#pragma unroll
    for (int i = 0; i < 16; i++) {
        int r = ty * 16 + i;
        t[r][tx] = in[(size_t)(k0 + r) * D_ + n0 + tx];
    }
    __syncthreads();
#pragma unroll
    for (int i = 0; i < 16; i++) {
        int r = ty * 16 + i;
        out[(size_t)(n0 + r) * D_ + k0 + tx] = f2b(t[tx][r]);
    }
}

// ---- QKV GEMM (reads fp32 X, converts in staging).
// Q: [B][H][S][64], pre-scaled by 0.125*log2(e);  K: [B][H][S][64];
// V: kv-tiled transpose [B][H][S/128][64][128]
__global__ __launch_bounds__(256, 2)
void gemm_qkv(const float* __restrict__ X,
              const unsigned short* __restrict__ Wt,   // [3][512][512] transposed bf16
              unsigned short* __restrict__ QKV) {
    const int z = blockIdx.z;
    const unsigned short* Bt = Wt + (size_t)z * D_ * D_;
    unsigned short* out = QKV + (size_t)z * M_ * D_;
    int m0 = blockIdx.x * 128, n0 = blockIdx.y * 128;
    int tid = threadIdx.x;
    int wave = tid >> 6, lane = tid & 63, l16 = lane & 15, quad = lane >> 4;
    int wm = (wave >> 1) * 64, wn = (wave & 1) * 64;

    __shared__ __align__(16) unsigned short As[128][40];
    __shared__ __align__(16) unsigned short Bs[128][40];

    f32x4 acc[4][4];
    const f32x4 zf = {0.f, 0.f, 0.f, 0.f};
#pragma unroll
    for (int i = 0; i < 4; i++)
#pragma unroll
        for (int j = 0; j < 4; j++) acc[i][j] = zf;

    for (int k0 = 0; k0 < D_; k0 += 32) {
        __syncthreads();
#pragma unroll
        for (int i = 0; i < 2; i++) {
            int c = tid + i * 256;
            int row = c >> 2, off = (c & 3) * 8;
            const float* xp = X + (size_t)(m0 + row) * D_ + k0 + off;
            float4 v0 = *(const float4*)xp;
            float4 v1 = *(const float4*)(xp + 4);
            short8 s;
            s[0] = f2b(v0.x); s[1] = f2b(v0.y); s[2] = f2b(v0.z); s[3] = f2b(v0.w);
            s[4] = f2b(v1.x); s[5] = f2b(v1.y); s[6] = f2b(v1.z); s[7] = f2b(v1.w);
            *(short8*)&As[row][off] = s;
            *(short8*)&Bs[row][off] = *(const short8*)(Bt + (size_t)(n0 + row) * D_ + k0 + off);
        }
        __syncthreads();
        short8 af[4], bf[4];
#pragma unroll
        for (int mt = 0; mt < 4; mt++) af[mt] = *(const short8*)&As[wm + mt * 16 + l16][quad * 8];
#pragma unroll
        for (int nt = 0; nt < 4; nt++) bf[nt] = *(const short8*)&Bs[wn + nt * 16 + l16][quad * 8];
#pragma unroll
        for (int mt = 0; mt < 4; mt++)
#pragma unroll
            for (int nt = 0; nt < 4; nt++)
                acc[mt][nt] = MFMA16(af[mt], bf[nt], acc[mt][nt]);
    }
    const float qscale = (z == 0) ? 0.18033688011112042f : 1.0f;  // 0.125*log2(e) folded into Q
    // epilogue: C/D layout col=lane&15, row=quad*4+r
#pragma unroll
    for (int mt = 0; mt < 4; mt++)
#pragma unroll
        for (int nt = 0; nt < 4; nt++)
#pragma unroll
            for (int r = 0; r < 4; r++) {
                int m = m0 + wm + mt * 16 + quad * 4 + r;
                int n = n0 + wn + nt * 16 + l16;
                int bb = m >> 11, ss = m & 2047, hh = n >> 6, dd = n & 63;
                size_t idx;
                if (z == 2) {
                    // kv-tiled V^T: [tile][dd][ss&127]
                    idx = (((size_t)bb * H_ + hh) * DP_) * S_
                        + (size_t)(ss >> 7) * (DP_ * 128) + dd * 128 + (ss & 127);
                } else {
                    idx = (((size_t)bb * H_ + hh) * S_ + ss) * DP_ + dd;
                }
                out[idx] = f2b(acc[mt][nt][r] * qscale);
            }
}

// ---------------- flash attention: barrier-free; CU-local (b,h) sharing; batched frag loads ----------------
__global__ __launch_bounds__(256, 4)
void flash_attn(const unsigned short* __restrict__ Qg, const unsigned short* __restrict__ Kg,
                const unsigned short* __restrict__ Vtg, unsigned short* __restrict__ ctx) {
    int bid = blockIdx.x;
    // (b,h) = bid & 31 so co-resident blocks (bid stride 256) share K/V tiles -> L1 reuse
    int hh = bid & 7, bb = (bid >> 3) & 3, qt = bid >> 5;
    int tid = threadIdx.x;
    int wave = tid >> 6, lane = tid & 63, l16 = lane & 15, quad = lane >> 4;

    size_t bh = ((size_t)bb * H_ + hh) * S_ * DP_;
    const unsigned short* Qb = Qg + bh;
    const unsigned short* Kb = Kg + bh;
    const unsigned short* Vb = Vtg + bh;   // kv-tiled V^T: [S/128][64][128]

    // per-wave P buffer; rows permuted so writes are ~free; reads b128 per row
    __shared__ __align__(16) unsigned short Ps[4][16][136];

    // Q A-fragments in registers for the whole kernel (already scaled by 0.125*log2e)
    short8 qf0, qf1;
    {
        const unsigned short* qp = Qb + (size_t)(qt * 64 + wave * 16 + l16) * DP_ + quad * 8;
        qf0 = *(const short8*)qp;
        qf1 = *(const short8*)(qp + 32);
    }

    const f32x4 zf = {0.f, 0.f, 0.f, 0.f};
    f32x4 oacc[4];          // O^T: row(quad*4+r)=d within ot*16 tile, col(l16)=q
#pragma unroll
    for (int i = 0; i < 4; i++) oacc[i] = zf;
    float mrow[4], lrow[4];  // per q = quad*4+r, log2 domain
#pragma unroll
    for (int r = 0; r < 4; r++) { mrow[r] = -1e30f; lrow[r] = 0.f; }
    const int rdrow = ((l16 & 3) << 2) | (l16 >> 2);
    const int bsrc = ((l16 >> 2) << 4) | l16;  // lane with quad = l16>>2
    const int rsel = l16 & 3;

    for (int it = 0; it < 16; it++) {
        int kv = it * 128;
        const unsigned short* Vtile = Vb + (size_t)it * (DP_ * 128);

        // batch all 16 K-fragment loads -> one vmcnt wait, loads overlap in flight
        short8 kf[16];
#pragma unroll
        for (int nt = 0; nt < 8; nt++) {
            const unsigned short* kp = Kb + (size_t)(kv + nt * 16 + l16) * DP_ + quad * 8;
            kf[2 * nt]     = *(const short8*)kp;
            kf[2 * nt + 1] = *(const short8*)(kp + 32);
        }
        f32x4 sacc[8];
#pragma unroll
        for (int nt = 0; nt < 8; nt++) {
            f32x4 s = MFMA16(qf0, kf[2 * nt], zf);
            sacc[nt] = MFMA16(qf1, kf[2 * nt + 1], s);
        }
        // issue first half of V fragments now (independent of softmax)
        short8 vfA[8];
#pragma unroll
        for (int kt = 0; kt < 2; kt++)
#pragma unroll
            for (int ot = 0; ot < 4; ot++)
                vfA[kt * 4 + ot] = *(const short8*)(Vtile + (ot * 16 + l16) * 128 + kt * 32 + quad * 8);

        // online softmax, log2 domain (scale pre-folded into Q)
        float alpha[4];
#pragma unroll
        for (int r = 0; r < 4; r++) {
            float mx = sacc[0][r];
#pragma unroll
            for (int nt = 1; nt < 8; nt++) mx = fmaxf(mx, sacc[nt][r]);
#pragma unroll
            for (int off = 1; off < 16; off <<= 1) mx = fmaxf(mx, __shfl_xor(mx, off));
            float mn = fmaxf(mrow[r], mx);
            alpha[r] = exp2f(mrow[r] - mn);
            mrow[r] = mn;
        }
        float rs[4] = {0.f, 0.f, 0.f, 0.f};
#pragma unroll
        for (int nt = 0; nt < 8; nt++)
#pragma unroll
            for (int r = 0; r < 4; r++) {
                float p = exp2f(sacc[nt][r] - mrow[r]);
                rs[r] += p;
                Ps[wave][(r << 2) | quad][nt * 16 + l16] = f2b(p);
            }
        // issue second half of V fragments (covers Ps write->read latency)
        short8 vfB[8];
#pragma unroll
        for (int kt = 2; kt < 4; kt++)
#pragma unroll
            for (int ot = 0; ot < 4; ot++)
                vfB[(kt - 2) * 4 + ot] = *(const short8*)(Vtile + (ot * 16 + l16) * 128 + kt * 32 + quad * 8);
#pragma unroll
        for (int r = 0; r < 4; r++) {
            float s = rs[r];
#pragma unroll
            for (int off = 1; off < 16; off <<= 1) s += __shfl_xor(s, off);
            lrow[r] = alpha[r] * lrow[r] + s;
        }
        // broadcast alpha (per q=quad*4+r) to lanes where q = l16
        float a0 = __shfl(alpha[0], bsrc), a1 = __shfl(alpha[1], bsrc);
        float a2 = __shfl(alpha[2], bsrc), a3 = __shfl(alpha[3], bsrc);
        float at = rsel == 0 ? a0 : rsel == 1 ? a1 : rsel == 2 ? a2 : a3;
#pragma unroll
        for (int ot = 0; ot < 4; ot++)
#pragma unroll
            for (int r = 0; r < 4; r++) oacc[ot][r] *= at;
        // O^T += V^T · P^T
#pragma unroll
        for (int kt = 0; kt < 4; kt++) {
            short8 pf = *(const short8*)&Ps[wave][rdrow][kt * 32 + quad * 8];
#pragma unroll
            for (int ot = 0; ot < 4; ot++) {
                short8 vf = (kt < 2) ? vfA[kt * 4 + ot] : vfB[(kt - 2) * 4 + ot];
                oacc[ot] = MFMA16(vf, pf, oacc[ot]);
            }
        }
    }
    // epilogue: divide by l (broadcast to q=l16 lanes), store O (merge heads), 8B stores
    float l0 = __shfl(lrow[0], bsrc), l1 = __shfl(lrow[1], bsrc);
    float l2 = __shfl(lrow[2], bsrc), l3 = __shfl(lrow[3], bsrc);
    float lt = rsel == 0 ? l0 : rsel == 1 ? l1 : rsel == 2 ? l2 : l3;
    float inv = 1.0f / lt;
    int srow = qt * 64 + wave * 16 + l16;
#pragma unroll
    for (int ot = 0; ot < 4; ot++) {
        ushort4 o;
        o.x = f2b(oacc[ot][0] * inv);
        o.y = f2b(oacc[ot][1] * inv);
        o.z = f2b(oacc[ot][2] * inv);
        o.w = f2b(oacc[ot][3] * inv);
        *(ushort4*)&ctx[((size_t)bb * S_ + srow) * D_ + hh * DP_ + ot * 16 + quad * 4] = o;
    }
}

// ---------------- output projection GEMM -> fp32 scratch ----------------
__global__ __launch_bounds__(256, 2)
void gemm_proj(const unsigned short* __restrict__ A,   // ctx [8192][512] bf16
               const unsigned short* __restrict__ Bt,  // Wo^T [512][512] bf16
               float* __restrict__ outf) {             // [8192][512] fp32
    int m0 = blockIdx.x * 128, n0 = blockIdx.y * 128;
    int tid = threadIdx.x;
    int wave = tid >> 6, lane = tid & 63, l16 = lane & 15, quad = lane >> 4;
    int wm = (wave >> 1) * 64, wn = (wave & 1) * 64;

    __shared__ __align__(16) unsigned short As[128][40];
    __shared__ __align__(16) unsigned short Bs[128][40];

    f32x4 acc[4][4];
    const f32x4 zf = {0.f, 0.f, 0.f, 0.f};
#pragma unroll
    for (int i = 0; i < 4; i++)
#pragma unroll
        for (int j = 0; j < 4; j++) acc[i][j] = zf;

    for (int k0 = 0; k0 < D_; k0 += 32) {
        __syncthreads();
#pragma unroll
        for (int i = 0; i < 2; i++) {
            int c = tid + i * 256;
            int row = c >> 2, off = (c & 3) * 8;
            *(short8*)&As[row][off] = *(const short8*)(A + (size_t)(m0 + row) * D_ + k0 + off);
            *(short8*)&Bs[row][off] = *(const short8*)(Bt + (size_t)(n0 + row) * D_ + k0 + off);
        }
        __syncthreads();
        short8 af[4], bf[4];
#pragma unroll
        for (int mt = 0; mt < 4; mt++) af[mt] = *(const short8*)&As[wm + mt * 16 + l16][quad * 8];
#pragma unroll
        for (int nt = 0; nt < 4; nt++) bf[nt] = *(const short8*)&Bs[wn + nt * 16 + l16][quad * 8];
#pragma unroll
        for (int mt = 0; mt < 4; mt++)
#pragma unroll
            for (int nt = 0; nt < 4; nt++)
                acc[mt][nt] = MFMA16(af[mt], bf[nt], acc[mt][nt]);
    }
#pragma unroll
    for (int mt = 0; mt < 4; mt++)
#pragma unroll
        for (int nt = 0; nt < 4; nt++)
#pragma unroll
            for (int r = 0; r < 4; r++) {
                int m = m0 + wm + mt * 16 + quad * 4 + r;
                int n = n0 + wn + nt * 16 + l16;
                outf[(size_t)m * D_ + n] = acc[mt][nt][r];
            }
}

// ---------------- bias + residual + LayerNorm (all fp32), one block per row ----------------
__global__ __launch_bounds__(256, 4)
void ln_out(const float* __restrict__ tmp, const float* __restrict__ Xg,
            const float* __restrict__ bo, const float* __restrict__ gamma,
            const float* __restrict__ beta, float* __restrict__ outp) {
    int row = blockIdx.x;
    int tid = threadIdx.x;
    int lane = tid & 63, wave = tid >> 6;
    float resid[2];
#pragma unroll
    for (int i = 0; i < 2; i++) {
        int c = tid + i * 256;
        resid[i] = Xg[(size_t)row * D_ + c] + tmp[(size_t)row * D_ + c] + bo[c];
    }
    float sum = resid[0] + resid[1];
    float sq = resid[0] * resid[0] + resid[1] * resid[1];
#pragma unroll
    for (int off = 1; off < 64; off <<= 1) {
        sum += __shfl_xor(sum, off);
        sq += __shfl_xor(sq, off);
    }
    __shared__ float red[8];
    if (lane == 0) { red[wave] = sum; red[4 + wave] = sq; }
    __syncthreads();
    sum = red[0] + red[1] + red[2] + red[3];
    sq = red[4] + red[5] + red[6] + red[7];
    float mu = sum * (1.0f / D_);
    float var = sq * (1.0f / D_) - mu * mu;
    float rstd = rsqrtf(var + 1e-6f);
#pragma unroll
    for (int i = 0; i < 2; i++) {
        int c = tid + i * 256;
        float o = (resid[i] - mu) * rstd * gamma[c] + beta[c];
        outp[(size_t)row * D_ + c] = o;
    }
}

extern "C" void kernel_launch(void* const* d_in, const int* in_sizes, int n_in,
                              void* d_out, int out_size, void* d_ws, size_t ws_size,
                              hipStream_t stream) {
    const float* x     = (const float*)d_in[0];
    const float* wq    = (const float*)d_in[1];
    const float* wk    = (const float*)d_in[2];
    const float* wv    = (const float*)d_in[3];
    const float* wo    = (const float*)d_in[4];
    const float* bo    = (const float*)d_in[5];
    const float* gamma = (const float*)d_in[6];
    const float* beta  = (const float*)d_in[7];
    float* out = (float*)d_out;

    // ws layout (34 MB): [wt 2MB | Q 8 | K 8 | V 8 | ctx 8]; fp32 tmp aliases Q+K (dead after flash)
    unsigned short* wt  = (unsigned short*)d_ws;
    unsigned short* Q   = wt + 4 * D_ * D_;
    unsigned short* K   = Q + (size_t)M_ * D_;
    unsigned short* V   = K + (size_t)M_ * D_;      // kv-tiled V^T [B][H][S/128][64][128]
    unsigned short* ctx = V + (size_t)M_ * D_;
    float* tmp = (float*)Q;                          // alias: Q,K dead after flash

    transpose_w<<<dim3(8, 8, 4), 256, 0, stream>>>(wq, wk, wv, wo, wt);
    gemm_qkv<<<dim3(64, 4, 3), 256, 0, stream>>>(x, wt, Q);
    flash_attn<<<dim3(1024), 256, 0, stream>>>(Q, K, V, ctx);
    gemm_proj<<<dim3(64, 4), 256, 0, stream>>>(ctx, wt + 3 * D_ * D_, tmp);
    ln_out<<<dim3(8192), 256, 0, stream>>>(tmp, x, bo, gamma, beta, out);
}

// Round 7
// 279.136 us; speedup vs baseline: 1.3052x; 1.3052x over previous
//
#include <hip/hip_runtime.h>
#include <hip/hip_bf16.h>

typedef __attribute__((ext_vector_type(8))) short short8;
typedef __attribute__((ext_vector_type(4))) float f32x4;

constexpr int B_ = 4, S_ = 2048, D_ = 512, H_ = 8, DP_ = 64;
constexpr int M_ = B_ * S_;  // 8192 rows

__device__ __forceinline__ unsigned short f2b(float f) {
    __hip_bfloat16 h = __float2bfloat16(f);
    return *reinterpret_cast<unsigned short*>(&h);
}

#define MFMA16(a, b, c) __builtin_amdgcn_mfma_f32_16x16x32_bf16((a), (b), (c), 0, 0, 0)

// ---------------- weight transpose + convert: Wt[n][k] = bf16(W[k][n]) ----------------
__global__ __launch_bounds__(256)
void transpose_w(const float* __restrict__ w0, const float* __restrict__ w1,
                 const float* __restrict__ w2, const float* __restrict__ w3,
                 unsigned short* __restrict__ outw) {
    const float* in = (blockIdx.z == 0) ? w0 : (blockIdx.z == 1) ? w1
                     : (blockIdx.z == 2) ? w2 : w3;
    unsigned short* out = outw + (size_t)blockIdx.z * D_ * D_;
    __shared__ float t[64][65];
    int k0 = blockIdx.x * 64, n0 = blockIdx.y * 64;
    int tx = threadIdx.x & 63, ty = threadIdx.x >> 6;
#pragma unroll
    for (int i = 0; i < 16; i++) {
        int r = ty * 16 + i;
        t[r][tx] = in[(size_t)(k0 + r) * D_ + n0 + tx];
    }
    __syncthreads();
#pragma unroll
    for (int i = 0; i < 16; i++) {
        int r = ty * 16 + i;
        out[(size_t)(n0 + r) * D_ + k0 + tx] = f2b(t[tx][r]);
    }
}

// ---- QKV GEMM (reads fp32 X, converts in staging).
// Q: [B][H][S][64], pre-scaled by 0.125*log2(e);  K: [B][H][S][64];
// V: kv-tiled transpose [B][H][S/128][64][128]
__global__ __launch_bounds__(256, 2)
void gemm_qkv(const float* __restrict__ X,
              const unsigned short* __restrict__ Wt,   // [3][512][512] transposed bf16
              unsigned short* __restrict__ QKV) {
    const int z = blockIdx.z;
    const unsigned short* Bt = Wt + (size_t)z * D_ * D_;
    unsigned short* out = QKV + (size_t)z * M_ * D_;
    int m0 = blockIdx.x * 128, n0 = blockIdx.y * 128;
    int tid = threadIdx.x;
    int wave = tid >> 6, lane = tid & 63, l16 = lane & 15, quad = lane >> 4;
    int wm = (wave >> 1) * 64, wn = (wave & 1) * 64;

    __shared__ __align__(16) unsigned short As[128][40];
    __shared__ __align__(16) unsigned short Bs[128][40];

    f32x4 acc[4][4];
    const f32x4 zf = {0.f, 0.f, 0.f, 0.f};
#pragma unroll
    for (int i = 0; i < 4; i++)
#pragma unroll
        for (int j = 0; j < 4; j++) acc[i][j] = zf;

    for (int k0 = 0; k0 < D_; k0 += 32) {
        __syncthreads();
#pragma unroll
        for (int i = 0; i < 2; i++) {
            int c = tid + i * 256;
            int row = c >> 2, off = (c & 3) * 8;
            const float* xp = X + (size_t)(m0 + row) * D_ + k0 + off;
            float4 v0 = *(const float4*)xp;
            float4 v1 = *(const float4*)(xp + 4);
            short8 s;
            s[0] = f2b(v0.x); s[1] = f2b(v0.y); s[2] = f2b(v0.z); s[3] = f2b(v0.w);
            s[4] = f2b(v1.x); s[5] = f2b(v1.y); s[6] = f2b(v1.z); s[7] = f2b(v1.w);
            *(short8*)&As[row][off] = s;
            *(short8*)&Bs[row][off] = *(const short8*)(Bt + (size_t)(n0 + row) * D_ + k0 + off);
        }
        __syncthreads();
        short8 af[4], bf[4];
#pragma unroll
        for (int mt = 0; mt < 4; mt++) af[mt] = *(const short8*)&As[wm + mt * 16 + l16][quad * 8];
#pragma unroll
        for (int nt = 0; nt < 4; nt++) bf[nt] = *(const short8*)&Bs[wn + nt * 16 + l16][quad * 8];
#pragma unroll
        for (int mt = 0; mt < 4; mt++)
#pragma unroll
            for (int nt = 0; nt < 4; nt++)
                acc[mt][nt] = MFMA16(af[mt], bf[nt], acc[mt][nt]);
    }
    const float qscale = (z == 0) ? 0.18033688011112042f : 1.0f;  // 0.125*log2(e) folded into Q
    // epilogue: C/D layout col=lane&15, row=quad*4+r
#pragma unroll
    for (int mt = 0; mt < 4; mt++)
#pragma unroll
        for (int nt = 0; nt < 4; nt++)
#pragma unroll
            for (int r = 0; r < 4; r++) {
                int m = m0 + wm + mt * 16 + quad * 4 + r;
                int n = n0 + wn + nt * 16 + l16;
                int bb = m >> 11, ss = m & 2047, hh = n >> 6, dd = n & 63;
                size_t idx;
                if (z == 2) {
                    // kv-tiled V^T: [tile][dd][ss&127]
                    idx = (((size_t)bb * H_ + hh) * DP_) * S_
                        + (size_t)(ss >> 7) * (DP_ * 128) + dd * 128 + (ss & 127);
                } else {
                    idx = (((size_t)bb * H_ + hh) * S_ + ss) * DP_ + dd;
                }
                out[idx] = f2b(acc[mt][nt][r] * qscale);
            }
}

// ---------------- flash attention: LDS V (b128 staged, reg-dbuf), CU-local bh sharing ----------------
__global__ __launch_bounds__(256, 4)
void flash_attn(const unsigned short* __restrict__ Qg, const unsigned short* __restrict__ Kg,
                const unsigned short* __restrict__ Vtg, unsigned short* __restrict__ ctx) {
    int bid = blockIdx.x;
    // (b,h) = bid & 31 so co-resident blocks (bid stride 256) share K/V tiles -> L1/L2 reuse
    int hh = bid & 7, bb = (bid >> 3) & 3, qt = bid >> 5;
    int tid = threadIdx.x;
    int wave = tid >> 6, lane = tid & 63, l16 = lane & 15, quad = lane >> 4;

    size_t bh = ((size_t)bb * H_ + hh) * S_ * DP_;
    const unsigned short* Qb = Qg + bh;
    const unsigned short* Kb = Kg + bh;
    const unsigned short* Vb = Vtg + bh;   // kv-tiled V^T: [S/128][64][128]

    __shared__ __align__(16) unsigned short Vts[DP_][136];   // padded: conflict-light b128 reads
    __shared__ __align__(16) unsigned short Ps[4][16][136];  // per-wave P

    // Q A-fragments in registers for the whole kernel (already scaled by 0.125*log2e)
    short8 qf0, qf1;
    {
        const unsigned short* qp = Qb + (size_t)(qt * 64 + wave * 16 + l16) * DP_ + quad * 8;
        qf0 = *(const short8*)qp;
        qf1 = *(const short8*)(qp + 32);
    }

    const f32x4 zf = {0.f, 0.f, 0.f, 0.f};
    f32x4 oacc[4];          // O^T: row(quad*4+r)=d within ot*16 tile, col(l16)=q
#pragma unroll
    for (int i = 0; i < 4; i++) oacc[i] = zf;
    float mrow[4], lrow[4];  // per q = quad*4+r, log2 domain
#pragma unroll
    for (int r = 0; r < 4; r++) { mrow[r] = -1e30f; lrow[r] = 0.f; }
    const int rdrow = ((l16 & 3) << 2) | (l16 >> 2);
    const int bsrc = ((l16 >> 2) << 4) | l16;  // lane with quad = l16>>2
    const int rsel = l16 & 3;
    const int srow0 = tid >> 4;                // staging row base (+16 per pass)
    const int scol = (tid & 15) * 8;           // staging column (shorts)

    // prologue: prefetch tile 0 into registers
    short8 vstage[4];
#pragma unroll
    for (int i = 0; i < 4; i++)
        vstage[i] = *(const short8*)(Vb + (size_t)(srow0 + i * 16) * 128 + scol);

    for (int it = 0; it < 16; it++) {
        int kv = it * 128;
        __syncthreads();   // all waves done reading Vts (previous tile); vstage loads drained
#pragma unroll
        for (int i = 0; i < 4; i++)
            *(short8*)&Vts[srow0 + i * 16][scol] = vstage[i];
        __syncthreads();   // Vts visible
        if (it + 1 < 16) { // issue next-tile loads now; consumed after next barrier
            const unsigned short* vnext = Vb + (size_t)(it + 1) * (DP_ * 128);
#pragma unroll
            for (int i = 0; i < 4; i++)
                vstage[i] = *(const short8*)(vnext + (size_t)(srow0 + i * 16) * 128 + scol);
        }

        // S = Q K^T : 16 q-rows x 128 keys (K frags direct from global, L1-hot via bh-remap)
        f32x4 sacc[8];
#pragma unroll
        for (int nt = 0; nt < 8; nt++) {
            const unsigned short* kp = Kb + (size_t)(kv + nt * 16 + l16) * DP_ + quad * 8;
            short8 kf0 = *(const short8*)kp;
            short8 kf1 = *(const short8*)(kp + 32);
            f32x4 s = MFMA16(qf0, kf0, zf);
            sacc[nt] = MFMA16(qf1, kf1, s);
        }
        // online softmax, log2 domain (scale pre-folded into Q)
        float alpha[4];
#pragma unroll
        for (int r = 0; r < 4; r++) {
            float mx = sacc[0][r];
#pragma unroll
            for (int nt = 1; nt < 8; nt++) mx = fmaxf(mx, sacc[nt][r]);
#pragma unroll
            for (int off = 1; off < 16; off <<= 1) mx = fmaxf(mx, __shfl_xor(mx, off));
            float mn = fmaxf(mrow[r], mx);
            alpha[r] = exp2f(mrow[r] - mn);
            mrow[r] = mn;
        }
        float rs[4] = {0.f, 0.f, 0.f, 0.f};
#pragma unroll
        for (int nt = 0; nt < 8; nt++)
#pragma unroll
            for (int r = 0; r < 4; r++) {
                float p = exp2f(sacc[nt][r] - mrow[r]);
                rs[r] += p;
                Ps[wave][(r << 2) | quad][nt * 16 + l16] = f2b(p);
            }
#pragma unroll
        for (int r = 0; r < 4; r++) {
            float s = rs[r];
#pragma unroll
            for (int off = 1; off < 16; off <<= 1) s += __shfl_xor(s, off);
            lrow[r] = alpha[r] * lrow[r] + s;
        }
        // broadcast alpha (per q=quad*4+r) to lanes where q = l16
        float a0 = __shfl(alpha[0], bsrc), a1 = __shfl(alpha[1], bsrc);
        float a2 = __shfl(alpha[2], bsrc), a3 = __shfl(alpha[3], bsrc);
        float at = rsel == 0 ? a0 : rsel == 1 ? a1 : rsel == 2 ? a2 : a3;
#pragma unroll
        for (int ot = 0; ot < 4; ot++)
#pragma unroll
            for (int r = 0; r < 4; r++) oacc[ot][r] *= at;
        // O^T += V^T · P^T : A = V^T from LDS, B = P row (per-wave LDS)
#pragma unroll
        for (int kt = 0; kt < 4; kt++) {
            short8 pf = *(const short8*)&Ps[wave][rdrow][kt * 32 + quad * 8];
#pragma unroll
            for (int ot = 0; ot < 4; ot++) {
                short8 vf = *(const short8*)&Vts[ot * 16 + l16][kt * 32 + quad * 8];
                oacc[ot] = MFMA16(vf, pf, oacc[ot]);
            }
        }
    }
    // epilogue: divide by l (broadcast to q=l16 lanes), store O (merge heads), 8B stores
    float l0 = __shfl(lrow[0], bsrc), l1 = __shfl(lrow[1], bsrc);
    float l2 = __shfl(lrow[2], bsrc), l3 = __shfl(lrow[3], bsrc);
    float lt = rsel == 0 ? l0 : rsel == 1 ? l1 : rsel == 2 ? l2 : l3;
    float inv = 1.0f / lt;
    int orow = qt * 64 + wave * 16 + l16;
#pragma unroll
    for (int ot = 0; ot < 4; ot++) {
        ushort4 o;
        o.x = f2b(oacc[ot][0] * inv);
        o.y = f2b(oacc[ot][1] * inv);
        o.z = f2b(oacc[ot][2] * inv);
        o.w = f2b(oacc[ot][3] * inv);
        *(ushort4*)&ctx[((size_t)bb * S_ + orow) * D_ + hh * DP_ + ot * 16 + quad * 4] = o;
    }
}

// ---------------- output projection GEMM -> fp32 scratch ----------------
__global__ __launch_bounds__(256, 2)
void gemm_proj(const unsigned short* __restrict__ A,   // ctx [8192][512] bf16
               const unsigned short* __restrict__ Bt,  // Wo^T [512][512] bf16
               float* __restrict__ outf) {             // [8192][512] fp32
    int m0 = blockIdx.x * 128, n0 = blockIdx.y * 128;
    int tid = threadIdx.x;
    int wave = tid >> 6, lane = tid & 63, l16 = lane & 15, quad = lane >> 4;
    int wm = (wave >> 1) * 64, wn = (wave & 1) * 64;

    __shared__ __align__(16) unsigned short As[128][40];
    __shared__ __align__(16) unsigned short Bs[128][40];

    f32x4 acc[4][4];
    const f32x4 zf = {0.f, 0.f, 0.f, 0.f};
#pragma unroll
    for (int i = 0; i < 4; i++)
#pragma unroll
        for (int j = 0; j < 4; j++) acc[i][j] = zf;

    for (int k0 = 0; k0 < D_; k0 += 32) {
        __syncthreads();
#pragma unroll
        for (int i = 0; i < 2; i++) {
            int c = tid + i * 256;
            int row = c >> 2, off = (c & 3) * 8;
            *(short8*)&As[row][off] = *(const short8*)(A + (size_t)(m0 + row) * D_ + k0 + off);
            *(short8*)&Bs[row][off] = *(const short8*)(Bt + (size_t)(n0 + row) * D_ + k0 + off);
        }
        __syncthreads();
        short8 af[4], bf[4];
#pragma unroll
        for (int mt = 0; mt < 4; mt++) af[mt] = *(const short8*)&As[wm + mt * 16 + l16][quad * 8];
#pragma unroll
        for (int nt = 0; nt < 4; nt++) bf[nt] = *(const short8*)&Bs[wn + nt * 16 + l16][quad * 8];
#pragma unroll
        for (int mt = 0; mt < 4; mt++)
#pragma unroll
            for (int nt = 0; nt < 4; nt++)
                acc[mt][nt] = MFMA16(af[mt], bf[nt], acc[mt][nt]);
    }
#pragma unroll
    for (int mt = 0; mt < 4; mt++)
#pragma unroll
        for (int nt = 0; nt < 4; nt++)
#pragma unroll
            for (int r = 0; r < 4; r++) {
                int m = m0 + wm + mt * 16 + quad * 4 + r;
                int n = n0 + wn + nt * 16 + l16;
                outf[(size_t)m * D_ + n] = acc[mt][nt][r];
            }
}

// ---------------- bias + residual + LayerNorm (all fp32), one block per row ----------------
__global__ __launch_bounds__(256, 4)
void ln_out(const float* __restrict__ tmp, const float* __restrict__ Xg,
            const float* __restrict__ bo, const float* __restrict__ gamma,
            const float* __restrict__ beta, float* __restrict__ outp) {
    int row = blockIdx.x;
    int tid = threadIdx.x;
    int lane = tid & 63, wave = tid >> 6;
    float resid[2];
#pragma unroll
    for (int i = 0; i < 2; i++) {
        int c = tid + i * 256;
        resid[i] = Xg[(size_t)row * D_ + c] + tmp[(size_t)row * D_ + c] + bo[c];
    }
    float sum = resid[0] + resid[1];
    float sq = resid[0] * resid[0] + resid[1] * resid[1];
#pragma unroll
    for (int off = 1; off < 64; off <<= 1) {
        sum += __shfl_xor(sum, off);
        sq += __shfl_xor(sq, off);
    }
    __shared__ float red[8];
    if (lane == 0) { red[wave] = sum; red[4 + wave] = sq; }
    __syncthreads();
    sum = red[0] + red[1] + red[2] + red[3];
    sq = red[4] + red[5] + red[6] + red[7];
    float mu = sum * (1.0f / D_);
    float var = sq * (1.0f / D_) - mu * mu;
    float rstd = rsqrtf(var + 1e-6f);
#pragma unroll
    for (int i = 0; i < 2; i++) {
        int c = tid + i * 256;
        float o = (resid[i] - mu) * rstd * gamma[c] + beta[c];
        outp[(size_t)row * D_ + c] = o;
    }
}

extern "C" void kernel_launch(void* const* d_in, const int* in_sizes, int n_in,
                              void* d_out, int out_size, void* d_ws, size_t ws_size,
                              hipStream_t stream) {
    const float* x     = (const float*)d_in[0];
    const float* wq    = (const float*)d_in[1];
    const float* wk    = (const float*)d_in[2];
    const float* wv    = (const float*)d_in[3];
    const float* wo    = (const float*)d_in[4];
    const float* bo    = (const float*)d_in[5];
    const float* gamma = (const float*)d_in[6];
    const float* beta  = (const float*)d_in[7];
    float* out = (float*)d_out;

    // ws layout (34 MB): [wt 2MB | Q 8 | K 8 | V 8 | ctx 8]; fp32 tmp aliases Q+K (dead after flash)
    unsigned short* wt  = (unsigned short*)d_ws;
    unsigned short* Q   = wt + 4 * D_ * D_;
    unsigned short* K   = Q + (size_t)M_ * D_;
    unsigned short* V   = K + (size_t)M_ * D_;      // kv-tiled V^T [B][H][S/128][64][128]
    unsigned short* ctx = V + (size_t)M_ * D_;
    float* tmp = (float*)Q;                          // alias: Q,K dead after flash

    transpose_w<<<dim3(8, 8, 4), 256, 0, stream>>>(wq, wk, wv, wo, wt);
    gemm_qkv<<<dim3(64, 4, 3), 256, 0, stream>>>(x, wt, Q);
    flash_attn<<<dim3(1024), 256, 0, stream>>>(Q, K, V, ctx);
    gemm_proj<<<dim3(64, 4), 256, 0, stream>>>(ctx, wt + 3 * D_ * D_, tmp);
    ln_out<<<dim3(8192), 256, 0, stream>>>(tmp, x, bo, gamma, beta, out);
}